// Round 8
// baseline (315.774 us; speedup 1.0000x reference)
//
#include <hip/hip_runtime.h>
#include <cstdint>

// Problem constants: B=16, S=1, Dm=4096, H=32, Hd=128, P=2048
#define DM 4096
#define NB 16
#define NH 32
#define HD 128
#define PP 2048
#define NCHUNK 32
#define CROWS 64     // PP / NCHUNK
#define PSTRIDE 132  // per-head partial: 128 o + m + s + 2 pad
#define KP 256       // gemv K-panel (floats per row per panel)
#define NPAN (DM / KP)

typedef __attribute__((ext_vector_type(8))) short bf16x8;
typedef __attribute__((ext_vector_type(4))) float f32x4;

__device__ inline f32x4 ntld4(const float* p) {
  return __builtin_nontemporal_load(reinterpret_cast<const f32x4*>(p));
}

// Pairwise truncation hi/lo bf16 split: hi = trunc16 (1 v_perm per pair),
// lo = x - hi (exact), lo -> bf16 RNE (1 v_cvt_pk_bf16_f32 per pair).
__device__ inline void split_pair(float x0, float x1, uint32_t& hpair,
                                  uint32_t& lpair) {
  uint32_t u0 = __float_as_uint(x0), u1 = __float_as_uint(x1);
  hpair = __builtin_amdgcn_perm(u1, u0, 0x07060302u);
  float l0 = x0 - __uint_as_float(u0 & 0xFFFF0000u);
  float l1 = x1 - __uint_as_float(u1 & 0xFFFF0000u);
  asm("v_cvt_pk_bf16_f32 %0, %1, %2" : "=v"(lpair) : "v"(l0), "v"(l1));
}

// O[b][col(jt+n)] = sum_d A[b][d] * W[jt+n][d], 16-wide column tile,
// 256 threads = 4 waves. W streamed via LDS (wave-contiguous 1KB row-segment
// loads), 2-deep register staging so the ds_write's vmcnt wait lands on loads
// issued a full iteration earlier (covered even at 1 block/CU).
template <bool ROPE>
__device__ inline void gemv16(const float* __restrict__ A,
                              const float* __restrict__ W,
                              float* __restrict__ O, int jt,
                              const float* __restrict__ fr,
                              const float* __restrict__ fi) {
  const int wave = threadIdx.x >> 6;
  const int lane = threadIdx.x & 63;
  const int m = lane & 15;   // A-row (batch) / W-row (output col) in tile
  const int kg = lane >> 4;  // k-group 0..3
  const float* arow = A + (size_t)m * DM;

  __shared__ float wt[2][16][KP + 4];
  __shared__ float red[4][256];
  f32x4 acc = {0.f, 0.f, 0.f, 0.f};

#define GROW(j) (W + (size_t)(jt + wave * 4 + (j)) * DM)
#define COMPUTE(P, BI)                                                        \
  {                                                                           \
    _Pragma("unroll") for (int s = 0; s < 2; ++s) {                           \
      const int kl = (wave << 6) + (s << 5) + kg * 8;                         \
      f32x4 wa = *(const f32x4*)&wt[BI][m][kl];                               \
      f32x4 wb = *(const f32x4*)&wt[BI][m][kl + 4];                           \
      f32x4 xa = *(const f32x4*)(arow + (P)*KP + kl);                         \
      f32x4 xb = *(const f32x4*)(arow + (P)*KP + kl + 4);                     \
      union { bf16x8 v; uint32_t d[4]; } ah, al, wh, wl;                      \
      split_pair(xa.x, xa.y, ah.d[0], al.d[0]);                               \
      split_pair(xa.z, xa.w, ah.d[1], al.d[1]);                               \
      split_pair(xb.x, xb.y, ah.d[2], al.d[2]);                               \
      split_pair(xb.z, xb.w, ah.d[3], al.d[3]);                               \
      split_pair(wa.x, wa.y, wh.d[0], wl.d[0]);                               \
      split_pair(wa.z, wa.w, wh.d[1], wl.d[1]);                               \
      split_pair(wb.x, wb.y, wh.d[2], wl.d[2]);                               \
      split_pair(wb.z, wb.w, wh.d[3], wl.d[3]);                               \
      acc = __builtin_amdgcn_mfma_f32_16x16x32_bf16(ah.v, wh.v, acc, 0, 0, 0);\
      acc = __builtin_amdgcn_mfma_f32_16x16x32_bf16(ah.v, wl.v, acc, 0, 0, 0);\
      acc = __builtin_amdgcn_mfma_f32_16x16x32_bf16(al.v, wh.v, acc, 0, 0, 0);\
    }                                                                         \
  }

  // prologue: panel 0 direct to LDS; panel 1 into stgA
  {
    f32x4 s0[4];
#pragma unroll
    for (int j = 0; j < 4; ++j) s0[j] = ntld4(GROW(j) + lane * 4);
#pragma unroll
    for (int j = 0; j < 4; ++j)
      *(f32x4*)&wt[0][wave * 4 + j][lane * 4] = s0[j];
  }
  f32x4 sA[4], sB[4];
#pragma unroll
  for (int j = 0; j < 4; ++j) sA[j] = ntld4(GROW(j) + KP + lane * 4);
  __syncthreads();

  for (int k = 0; k < NPAN / 2; ++k) {
    const int p0 = 2 * k;
    if (p0 + 2 < NPAN) {
#pragma unroll
      for (int j = 0; j < 4; ++j)
        sB[j] = ntld4(GROW(j) + (p0 + 2) * KP + lane * 4);
    }
    COMPUTE(p0, 0);
#pragma unroll
    for (int j = 0; j < 4; ++j)
      *(f32x4*)&wt[1][wave * 4 + j][lane * 4] = sA[j];  // panel p0+1
    __syncthreads();
    const int p1 = p0 + 1;
    if (p1 + 2 < NPAN) {
#pragma unroll
      for (int j = 0; j < 4; ++j)
        sA[j] = ntld4(GROW(j) + (p1 + 2) * KP + lane * 4);
    }
    COMPUTE(p1, 1);
    if (p1 + 1 < NPAN) {
#pragma unroll
      for (int j = 0; j < 4; ++j)
        *(f32x4*)&wt[0][wave * 4 + j][lane * 4] = sB[j];  // panel p1+1
    }
    __syncthreads();
  }
#undef GROW
#undef COMPUTE

  // cross-wave reduce: D layout n = lane&15, mrow = (lane>>4)*4 + reg
  red[wave][lane * 4 + 0] = acc[0];
  red[wave][lane * 4 + 1] = acc[1];
  red[wave][lane * 4 + 2] = acc[2];
  red[wave][lane * 4 + 3] = acc[3];
  __syncthreads();
  const int t = threadIdx.x;
  float s = red[0][t] + red[1][t] + red[2][t] + red[3][t];
  float part = 0.f;
  if (ROPE) {
    __syncthreads();
    red[0][t] = s;
    __syncthreads();
    part = red[0][t ^ 4];  // pair-partner (adjacent output col)
  }
  const int l = t >> 2, r = t & 3;
  const int bb = ((l >> 4) << 2) + r;  // batch row of D
  const int n = l & 15;                // column within tile
  const int c = jt + n;
  float val;
  int oc;
  if (ROPE) {
    const int j = (c & 127) >> 1;
    const float f_r = fr[j], f_i = fi[j];
    if ((c & 1) == 0) {
      val = s * f_r - part * f_i;
      oc = (c & ~127) + j;
    } else {
      val = part * f_i + s * f_r;
      oc = (c & ~127) + 64 + j;
    }
  } else {
    val = s;
    oc = c;
  }
  O[(size_t)bb * DM + oc] = val;
}

__global__ __launch_bounds__(256) void qkv_proj_kernel(
    const float* __restrict__ x, const float* __restrict__ wq,
    const float* __restrict__ wk, const float* __restrict__ wv,
    const float* __restrict__ fr, const float* __restrict__ fi,
    float* __restrict__ oq, float* __restrict__ ok, float* __restrict__ ov,
    int* __restrict__ cnt) {
  if (blockIdx.x == 0 && threadIdx.x < NB) cnt[threadIdx.x] = 0;
  const int g = blockIdx.x >> 8;
  const int jt = (blockIdx.x & 255) << 4;
  if (g == 0)
    gemv16<true>(x, wq, oq, jt, fr, fi);
  else if (g == 1)
    gemv16<true>(x, wk, ok, jt, fr, fi);
  else
    gemv16<false>(x, wv, ov, jt, nullptr, nullptr);
}

__global__ __launch_bounds__(256) void oproj_kernel(
    const float* __restrict__ a, const float* __restrict__ w,
    float* __restrict__ o) {
  gemv16<false>(a, w, o, blockIdx.x << 4, nullptr, nullptr);
}

// One block per (b, chunk): single-pass online-softmax over 64 rows, K and V
// streamed interleaved (wave-contiguous 1KB/instr). Last block per batch
// (device-scope counter) merges all 32 chunk partials + the new position.
__global__ __launch_bounds__(512) void attn_chunk_kernel(
    const float* __restrict__ qrope, const float* __restrict__ krope,
    const float* __restrict__ vraw, const float* __restrict__ cache_k,
    const float* __restrict__ cache_v, float* __restrict__ part,
    int* __restrict__ cnt, float* __restrict__ aout) {
  const int b = blockIdx.x >> 5;
  const int c = blockIdx.x & 31;
  const int t = threadIdx.x;
  const f32x4 qa = *(const f32x4*)(qrope + (size_t)b * DM + 4 * t);
  const f32x4 qb = *(const f32x4*)(qrope + (size_t)b * DM + 2048 + 4 * t);
  const int h1 = t >> 5, h2 = h1 + 16;
  const float scale = 0.08838834764831845f;  // 1/sqrt(128)

  const float* Kb = cache_k + ((size_t)b * PP + (size_t)c * CROWS) * DM;
  const float* Vb = cache_v + ((size_t)b * PP + (size_t)c * CROWS) * DM;

  float m1 = -1e30f, s1 = 0.f, m2 = -1e30f, s2 = 0.f;
  f32x4 a1 = {0.f, 0.f, 0.f, 0.f}, a2 = {0.f, 0.f, 0.f, 0.f};
#pragma unroll 2
  for (int r = 0; r < CROWS; ++r) {
    const float* krow = Kb + (size_t)r * DM + 4 * t;
    const float* vrow = Vb + (size_t)r * DM + 4 * t;
    f32x4 k1 = ntld4(krow);
    f32x4 k2 = ntld4(krow + 2048);
    f32x4 v1 = ntld4(vrow);
    f32x4 v2 = ntld4(vrow + 2048);
    float p1 = qa.x * k1.x + qa.y * k1.y + qa.z * k1.z + qa.w * k1.w;
    float p2 = qb.x * k2.x + qb.y * k2.y + qb.z * k2.z + qb.w * k2.w;
#pragma unroll
    for (int off = 1; off <= 16; off <<= 1) {
      p1 += __shfl_xor(p1, off);
      p2 += __shfl_xor(p2, off);
    }
    p1 *= scale;
    p2 *= scale;
    float n1 = fmaxf(m1, p1);
    float c1 = __expf(m1 - n1), w1 = __expf(p1 - n1);
    s1 = s1 * c1 + w1;
    a1 = a1 * c1 + w1 * v1;
    m1 = n1;
    float n2 = fmaxf(m2, p2);
    float c2 = __expf(m2 - n2), w2 = __expf(p2 - n2);
    s2 = s2 * c2 + w2;
    a2 = a2 * c2 + w2 * v2;
    m2 = n2;
  }
  float* pb = part + (size_t)(b * NCHUNK + c) * NH * PSTRIDE;
  const int dbase = (4 * t) & 127;
  *(f32x4*)(pb + h1 * PSTRIDE + dbase) = a1;
  *(f32x4*)(pb + h2 * PSTRIDE + dbase) = a2;
  if ((t & 31) == 0) {
    pb[h1 * PSTRIDE + 128] = m1;
    pb[h1 * PSTRIDE + 129] = s1;
    pb[h2 * PSTRIDE + 128] = m2;
    pb[h2 * PSTRIDE + 129] = s2;
  }

  // last-block-per-batch combine (device-scope counter + release/acquire)
  __syncthreads();  // drains all part writes to L2 (barrier waits vmcnt)
  __shared__ int lastf;
  if (t == 0) {
    __threadfence();  // release: part writes visible device-wide
    lastf = (atomicAdd(&cnt[b], 1) == NCHUNK - 1) ? 1 : 0;
  }
  __syncthreads();
  if (!lastf) return;
  __threadfence();  // acquire: invalidate stale cached part lines

  const int h = t >> 4;
  const int d0 = (t & 15) * 8;
  const size_t qo = (size_t)b * DM + h * HD + d0;
  float pd = 0.f;
#pragma unroll
  for (int j = 0; j < 8; ++j) pd += qrope[qo + j] * krope[qo + j];
  pd += __shfl_xor(pd, 1);
  pd += __shfl_xor(pd, 2);
  pd += __shfl_xor(pd, 4);
  pd += __shfl_xor(pd, 8);
  const float snew = pd * scale;
  const float* pball = part + (size_t)b * NCHUNK * NH * PSTRIDE + h * PSTRIDE;
  float M = snew;
#pragma unroll 4
  for (int cc = 0; cc < NCHUNK; ++cc)
    M = fmaxf(M, pball[(size_t)cc * NH * PSTRIDE + 128]);
  const float en = __expf(snew - M);
  float S = en;
  f32x4 A1 = {0.f, 0.f, 0.f, 0.f}, A2 = {0.f, 0.f, 0.f, 0.f};
#pragma unroll 4
  for (int cc = 0; cc < NCHUNK; ++cc) {
    const float* pc = pball + (size_t)cc * NH * PSTRIDE;
    float e = __expf(pc[128] - M);
    S += e * pc[129];
    A1 += e * *(const f32x4*)(pc + d0);
    A2 += e * *(const f32x4*)(pc + d0 + 4);
  }
  f32x4 vn1 = *(const f32x4*)(vraw + qo);
  f32x4 vn2 = *(const f32x4*)(vraw + qo + 4);
  A1 += en * vn1;
  A2 += en * vn2;
  const float inv = 1.0f / S;
  *(f32x4*)(aout + qo) = A1 * inv;
  *(f32x4*)(aout + qo + 4) = A2 * inv;
}

extern "C" void kernel_launch(void* const* d_in, const int* in_sizes, int n_in,
                              void* d_out, int out_size, void* d_ws, size_t ws_size,
                              hipStream_t stream) {
  const float* x = (const float*)d_in[0];
  const float* cache_k = (const float*)d_in[1];
  const float* cache_v = (const float*)d_in[2];
  const float* fr = (const float*)d_in[3];
  const float* fi = (const float*)d_in[4];
  const float* dwq = (const float*)d_in[5];
  const float* dwk = (const float*)d_in[6];
  const float* dwv = (const float*)d_in[7];
  const float* dwo = (const float*)d_in[8];
  float* out = (float*)d_out;

  float* qrope = (float*)d_ws;          // 16*4096 (RoPE'd q, final layout)
  float* krope = qrope + NB * DM;       // 16*4096 (RoPE'd new k)
  float* vraw = krope + NB * DM;        // 16*4096 (new v)
  float* aout = vraw + NB * DM;         // 16*4096 (attention output)
  float* part = aout + NB * DM;         // 16*32*32*132 chunk partials
  int* cnt = (int*)(part + (size_t)NB * NCHUNK * NH * PSTRIDE);  // 16 counters

  qkv_proj_kernel<<<768, 256, 0, stream>>>(x, dwq, dwk, dwv, fr, fi,
                                           qrope, krope, vraw, cnt);
  attn_chunk_kernel<<<512, 512, 0, stream>>>(qrope, krope, vraw, cache_k,
                                             cache_v, part, cnt, aout);
  oproj_kernel<<<256, 256, 0, stream>>>(aout, dwo, out);
}

// Round 9
// 240.611 us; speedup vs baseline: 1.3124x; 1.3124x over previous
//
#include <hip/hip_runtime.h>
#include <cstdint>

// Problem constants: B=16, S=1, Dm=4096, H=32, Hd=128, P=2048
#define DM 4096
#define NB 16
#define NH 32
#define HD 128
#define PP 2048
#define NCHUNK 32
#define CROWS 64     // PP / NCHUNK
#define PSTRIDE 132  // per-head partial: 128 o + m + s + 2 pad

typedef __attribute__((ext_vector_type(8))) short bf16x8;
typedef __attribute__((ext_vector_type(4))) float f32x4;

__device__ inline float bf2f(short s) {
  return __uint_as_float(((uint32_t)(uint16_t)s) << 16);
}
__device__ inline f32x4 ntld4(const float* p) {
  return __builtin_nontemporal_load(reinterpret_cast<const f32x4*>(p));
}

// Pairwise truncation hi/lo bf16 split:
//   hi = trunc16(x) (1 v_perm per pair), lo = x - hi (exact), lo -> bf16 RNE
//   (1 v_cvt_pk_bf16_f32 per pair). dst dword = {elem0 lo16, elem1 hi16}.
__device__ inline void split_pair(float x0, float x1, uint32_t& hpair,
                                  uint32_t& lpair) {
  uint32_t u0 = __float_as_uint(x0), u1 = __float_as_uint(x1);
  hpair = __builtin_amdgcn_perm(u1, u0, 0x07060302u);
  float l0 = x0 - __uint_as_float(u0 & 0xFFFF0000u);
  float l1 = x1 - __uint_as_float(u1 & 0xFFFF0000u);
  asm("v_cvt_pk_bf16_f32 %0, %1, %2" : "=v"(lpair) : "v"(l0), "v"(l1));
}

// O[b][col(jt+n)] = sum_d A[b][d] * W[jt+n][d], 16-wide column tile.
// NW waves split K. ROPE: rotary remap applied to the output columns.
template <int NW, bool ROPE>
__device__ inline void gemv16(const float* __restrict__ A,
                              const float* __restrict__ W,
                              float* __restrict__ O, int jt,
                              const float* __restrict__ fr,
                              const float* __restrict__ fi) {
  const int wave = threadIdx.x >> 6;
  const int lane = threadIdx.x & 63;
  const int m = lane & 15;   // A-row (batch) / W-row (output col) in tile
  const int kg = lane >> 4;  // k-group 0..3
  const float* arow = A + (size_t)m * DM;
  const float* wrow = W + (size_t)(jt + m) * DM;
  const int kbase = wave * (DM / NW) + kg * 8;
  f32x4 acc = {0.f, 0.f, 0.f, 0.f};
#pragma unroll 2
  for (int kb = 0; kb < (DM / NW) / 32; ++kb) {
    const int k = kbase + kb * 32;
    f32x4 xa = *(const f32x4*)(arow + k);
    f32x4 xb = *(const f32x4*)(arow + k + 4);
    f32x4 wa = ntld4(wrow + k);
    f32x4 wb = ntld4(wrow + k + 4);
    union { bf16x8 v; uint32_t d[4]; } ah, al, wh, wl;
    split_pair(xa.x, xa.y, ah.d[0], al.d[0]);
    split_pair(xa.z, xa.w, ah.d[1], al.d[1]);
    split_pair(xb.x, xb.y, ah.d[2], al.d[2]);
    split_pair(xb.z, xb.w, ah.d[3], al.d[3]);
    split_pair(wa.x, wa.y, wh.d[0], wl.d[0]);
    split_pair(wa.z, wa.w, wh.d[1], wl.d[1]);
    split_pair(wb.x, wb.y, wh.d[2], wl.d[2]);
    split_pair(wb.z, wb.w, wh.d[3], wl.d[3]);
    acc = __builtin_amdgcn_mfma_f32_16x16x32_bf16(ah.v, wh.v, acc, 0, 0, 0);
    acc = __builtin_amdgcn_mfma_f32_16x16x32_bf16(ah.v, wl.v, acc, 0, 0, 0);
    acc = __builtin_amdgcn_mfma_f32_16x16x32_bf16(al.v, wh.v, acc, 0, 0, 0);
  }
  __shared__ float red[NW][256];
  red[wave][lane * 4 + 0] = acc[0];
  red[wave][lane * 4 + 1] = acc[1];
  red[wave][lane * 4 + 2] = acc[2];
  red[wave][lane * 4 + 3] = acc[3];
  __syncthreads();
  const int t = threadIdx.x;
  float s = 0.f;
  if (t < 256) {
#pragma unroll
    for (int w = 0; w < NW; ++w) s += red[w][t];
  }
  float part = 0.f;
  if (ROPE) {
    __syncthreads();
    if (t < 256) red[0][t] = s;
    __syncthreads();
    if (t < 256) part = red[0][t ^ 4];  // pair-partner (adjacent output col)
  }
  if (t < 256) {
    const int l = t >> 2, r = t & 3;
    const int bb = ((l >> 4) << 2) + r;  // batch row of D
    const int n = l & 15;                // column within tile
    const int c = jt + n;
    float val;
    int oc;
    if (ROPE) {
      const int j = (c & 127) >> 1;
      const float f_r = fr[j], f_i = fi[j];
      if ((c & 1) == 0) {  // even col: s = x_even, part = x_odd
        val = s * f_r - part * f_i;
        oc = (c & ~127) + j;
      } else {             // odd col: part = x_even, s = x_odd
        val = part * f_i + s * f_r;
        oc = (c & ~127) + 64 + j;
      }
    } else {
      val = s;
      oc = c;
    }
    O[(size_t)bb * DM + oc] = val;
  }
}

__global__ __launch_bounds__(256) void qkv_proj_kernel(
    const float* __restrict__ x, const float* __restrict__ wq,
    const float* __restrict__ wk, const float* __restrict__ wv,
    const float* __restrict__ fr, const float* __restrict__ fi,
    float* __restrict__ oq, float* __restrict__ ok, float* __restrict__ ov) {
  const int g = blockIdx.x >> 8;
  const int jt = (blockIdx.x & 255) << 4;
  if (g == 0)
    gemv16<4, true>(x, wq, oq, jt, fr, fi);
  else if (g == 1)
    gemv16<4, true>(x, wk, ok, jt, fr, fi);
  else
    gemv16<4, false>(x, wv, ov, jt, nullptr, nullptr);
}

__global__ __launch_bounds__(1024, 4) void oproj_kernel(
    const float* __restrict__ a, const float* __restrict__ w,
    float* __restrict__ o) {
  gemv16<16, false>(a, w, o, blockIdx.x << 4, nullptr, nullptr);
}

// One block per (b, chunk): streams K[b][c*64..+64][*][*] (1MB contiguous) then
// V likewise. Wave-contiguous loads: thread t reads float4 at 4t and 4t+2048
// (heads t>>5 and (t>>5)+16) -> every load instruction covers a contiguous
// 1KB-per-wave segment. 32-lane shuffle reductions (VALU is ~4% busy; free).
__global__ __launch_bounds__(512) void attn_chunk_kernel(
    const float* __restrict__ qrope, const float* __restrict__ cache_k,
    const float* __restrict__ cache_v, float* __restrict__ part) {
  const int b = blockIdx.x >> 5;
  const int c = blockIdx.x & 31;
  const int t = threadIdx.x;
  __shared__ float sc[NH][CROWS];

  const f32x4 qa = *(const f32x4*)(qrope + (size_t)b * DM + 4 * t);
  const f32x4 qb = *(const f32x4*)(qrope + (size_t)b * DM + 2048 + 4 * t);
  const int h1 = t >> 5;
  const int h2 = h1 + 16;
  const float scale = 0.08838834764831845f;  // 1/sqrt(128)

  const float* Kb = cache_k + ((size_t)b * PP + (size_t)c * CROWS) * DM;
#pragma unroll 2
  for (int r = 0; r < CROWS; ++r) {
    const float* krow = Kb + (size_t)r * DM + 4 * t;
    f32x4 k1 = ntld4(krow);
    f32x4 k2 = ntld4(krow + 2048);
    float p1 = qa.x * k1.x + qa.y * k1.y + qa.z * k1.z + qa.w * k1.w;
    float p2 = qb.x * k2.x + qb.y * k2.y + qb.z * k2.z + qb.w * k2.w;
#pragma unroll
    for (int off = 1; off <= 16; off <<= 1) {
      p1 += __shfl_xor(p1, off);
      p2 += __shfl_xor(p2, off);
    }
    if ((t & 31) == 0) {
      sc[h1][r] = p1 * scale;
      sc[h2][r] = p2 * scale;
    }
  }
  __syncthreads();

  // per-head chunk-local softmax: 16 threads per head, 4 scores each
  const int hh = t >> 4, u = t & 15;
  float4 sv4 = *(const float4*)(&sc[hh][u * 4]);
  float mx = fmaxf(fmaxf(sv4.x, sv4.y), fmaxf(sv4.z, sv4.w));
#pragma unroll
  for (int off = 1; off <= 8; off <<= 1) mx = fmaxf(mx, __shfl_xor(mx, off));
  float e0 = __expf(sv4.x - mx), e1 = __expf(sv4.y - mx);
  float e2 = __expf(sv4.z - mx), e3 = __expf(sv4.w - mx);
  float4 ev = {e0, e1, e2, e3};
  *(float4*)(&sc[hh][u * 4]) = ev;  // in-place: e values replace scores
  float sm = (e0 + e1) + (e2 + e3);
#pragma unroll
  for (int off = 1; off <= 8; off <<= 1) sm += __shfl_xor(sm, off);
  float* pb = part + ((size_t)(b * NCHUNK + c) * NH) * PSTRIDE;
  if (u == 0) {
    pb[hh * PSTRIDE + 128] = mx;
    pb[hh * PSTRIDE + 129] = sm;
  }
  __syncthreads();

  // PV: same thread->dim mapping as score phase
  const float* Vb = cache_v + ((size_t)b * PP + (size_t)c * CROWS) * DM;
  f32x4 a1 = {0.f, 0.f, 0.f, 0.f}, a2 = {0.f, 0.f, 0.f, 0.f};
#pragma unroll 2
  for (int r = 0; r < CROWS; ++r) {
    const float* vrow = Vb + (size_t)r * DM + 4 * t;
    f32x4 v1 = ntld4(vrow);
    f32x4 v2 = ntld4(vrow + 2048);
    float w1 = sc[h1][r], w2 = sc[h2][r];
    a1 += w1 * v1;
    a2 += w2 * v2;
  }
  const int dbase = (4 * t) & 127;
  *(f32x4*)(pb + h1 * PSTRIDE + dbase) = a1;
  *(f32x4*)(pb + h2 * PSTRIDE + dbase) = a2;
}

// One block per (b, h): merge 32 chunk partials + the appended position.
__global__ __launch_bounds__(128) void attn_combine_kernel(
    const float* __restrict__ qrope, const float* __restrict__ krope,
    const float* __restrict__ vraw, const float* __restrict__ part,
    float* __restrict__ aout) {
  const int b = blockIdx.x >> 5;
  const int h = blockIdx.x & 31;
  const int d = threadIdx.x;
  __shared__ float red2[2];
  __shared__ float mv[NCHUNK], sv[NCHUNK], ec[NCHUNK];
  const size_t qoff = (size_t)b * DM + h * HD + d;
  float p = qrope[qoff] * krope[qoff];
#pragma unroll
  for (int off = 1; off <= 32; off <<= 1) p += __shfl_xor(p, off);
  if ((d & 63) == 0) red2[d >> 6] = p;
  const float* pb = part + ((size_t)b * NCHUNK * NH + h) * PSTRIDE;
  if (d < NCHUNK) {
    mv[d] = pb[(size_t)d * NH * PSTRIDE + 128];
    sv[d] = pb[(size_t)d * NH * PSTRIDE + 129];
  }
  __syncthreads();
  const float scale = 0.08838834764831845f;
  const float snew = (red2[0] + red2[1]) * scale;
  float M = snew;
#pragma unroll
  for (int c = 0; c < NCHUNK; ++c) M = fmaxf(M, mv[c]);
  if (d < NCHUNK) ec[d] = __expf(mv[d] - M);
  __syncthreads();
  const float en = __expf(snew - M);
  float S = en;
  float acc = en * vraw[qoff];
#pragma unroll 4
  for (int c = 0; c < NCHUNK; ++c) {
    acc += ec[c] * pb[(size_t)c * NH * PSTRIDE + d];
    S += ec[c] * sv[c];
  }
  aout[qoff] = acc / S;
}

extern "C" void kernel_launch(void* const* d_in, const int* in_sizes, int n_in,
                              void* d_out, int out_size, void* d_ws, size_t ws_size,
                              hipStream_t stream) {
  const float* x = (const float*)d_in[0];
  const float* cache_k = (const float*)d_in[1];
  const float* cache_v = (const float*)d_in[2];
  const float* fr = (const float*)d_in[3];
  const float* fi = (const float*)d_in[4];
  const float* dwq = (const float*)d_in[5];
  const float* dwk = (const float*)d_in[6];
  const float* dwv = (const float*)d_in[7];
  const float* dwo = (const float*)d_in[8];
  float* out = (float*)d_out;

  float* qrope = (float*)d_ws;          // 16*4096 (RoPE'd q, final layout)
  float* krope = qrope + NB * DM;       // 16*4096 (RoPE'd new k)
  float* vraw = krope + NB * DM;        // 16*4096 (new v)
  float* aout = vraw + NB * DM;         // 16*4096 (attention output)
  float* part = aout + NB * DM;         // 16*32*32*132 chunk partials

  qkv_proj_kernel<<<768, 256, 0, stream>>>(x, dwq, dwk, dwv, fr, fi,
                                           qrope, krope, vraw);
  attn_chunk_kernel<<<512, 512, 0, stream>>>(qrope, cache_k, cache_v, part);
  attn_combine_kernel<<<512, 128, 0, stream>>>(qrope, krope, vraw, part, aout);
  oproj_kernel<<<256, 1024, 0, stream>>>(aout, dwo, out);
}